// Round 6
// baseline (108.019 us; speedup 1.0000x reference)
//
#include <hip/hip_runtime.h>
#include <hip/hip_bf16.h>

#define NMAX 2048
#define HH 128
#define WW 128
#define NEARP 0.1f

// Runtime-adaptive input load: reference ships fp32; guard against a bf16
// dataset variant. Detected from intrinsics[0] (==150.0 iff fp32; bf16-packed
// bytes read as float give a denormal ~2e-41).
static __device__ __forceinline__ float ldin(const void* p, int i, bool is32) {
    return is32 ? ((const float*)p)[i]
                : __bfloat162float(((const __hip_bfloat16*)p)[i]);
}
static __device__ __forceinline__ bool detect32(const void* intr) {
    return ((const float*)intr)[0] > 1.0f;
}
static __device__ __forceinline__ void stout(void* out, int i, float v, bool is32) {
    if (is32) ((float*)out)[i] = v;
    else      ((__hip_bfloat16*)out)[i] = __float2bfloat16(v);
}

// Record layout (12 floats, 3x float4):
// [0]=u [1]=v [2]=na(=-0.5*cA) [3]=nb(=-cB) [4]=nc(=-0.5*cC) [5]=op
// [6]=cr [7]=cg [8]=cb [9..11] pad
// pwr = na*dx^2 + nb*dx*dy + nc*dy^2   (same value as reference form)

// Full per-gaussian preprocess -> 12-float record.
static __device__ void preprocess_one(
    const void* means, const void* log_scales, const void* rots,
    const void* colors, const void* opac, const void* intr, const void* c2w,
    int i, bool is32, float* rec)
{
    float Rwc[3][3], twc[3];
    {
        float Rcw[3][3], tcw[3];
        for (int r = 0; r < 3; ++r) {
            for (int c = 0; c < 3; ++c) Rcw[r][c] = ldin(c2w, r * 4 + c, is32);
            tcw[r] = ldin(c2w, r * 4 + 3, is32);
        }
        for (int r = 0; r < 3; ++r)
            for (int c = 0; c < 3; ++c) Rwc[r][c] = Rcw[c][r];
        for (int r = 0; r < 3; ++r)
            twc[r] = -(Rwc[r][0] * tcw[0] + Rwc[r][1] * tcw[1] + Rwc[r][2] * tcw[2]);
    }
    float fx = ldin(intr, 0, is32), fy = ldin(intr, 4, is32);
    float cx = ldin(intr, 2, is32), cy = ldin(intr, 5, is32);

    float mx = ldin(means, 3 * i, is32), my = ldin(means, 3 * i + 1, is32),
          mz = ldin(means, 3 * i + 2, is32);
    float px = Rwc[0][0] * mx + Rwc[0][1] * my + Rwc[0][2] * mz + twc[0];
    float py = Rwc[1][0] * mx + Rwc[1][1] * my + Rwc[1][2] * mz + twc[1];
    float pz = Rwc[2][0] * mx + Rwc[2][1] * my + Rwc[2][2] * mz + twc[2];
    bool valid = pz > NEARP;
    float zc = fmaxf(pz, NEARP);
    float izc = 1.0f / zc;
    float u = fx * px * izc + cx;
    float v = fy * py * izc + cy;

    float qw = ldin(rots, 4 * i, is32), qx = ldin(rots, 4 * i + 1, is32),
          qy = ldin(rots, 4 * i + 2, is32), qz = ldin(rots, 4 * i + 3, is32);
    float nrm = sqrtf(qw * qw + qx * qx + qy * qy + qz * qz);
    float inv = 1.0f / fmaxf(nrm, 1e-8f);
    qw *= inv; qx *= inv; qy *= inv; qz *= inv;
    float xx = qx * qx, yy = qy * qy, zz = qz * qz;
    float xy = qx * qy, xz = qx * qz, yz = qy * qz;
    float wx = qw * qx, wy = qw * qy, wz = qw * qz;
    float R[3][3] = {
        {1.f - 2.f * (yy + zz), 2.f * (xy - wz),       2.f * (xz + wy)},
        {2.f * (xy + wz),       1.f - 2.f * (xx + zz), 2.f * (yz - wx)},
        {2.f * (xz - wy),       2.f * (yz + wx),       1.f - 2.f * (xx + yy)}
    };
    float s2[3];
    for (int k = 0; k < 3; ++k) s2[k] = __expf(2.0f * ldin(log_scales, 3 * i + k, is32));

    float M[3][3];
    for (int r = 0; r < 3; ++r)
        for (int c = 0; c < 3; ++c)
            M[r][c] = R[r][0] * s2[0] * R[c][0] + R[r][1] * s2[1] * R[c][1]
                    + R[r][2] * s2[2] * R[c][2];
    M[0][0] += 1e-6f; M[1][1] += 1e-6f; M[2][2] += 1e-6f;

    float TM[3][3];
    for (int r = 0; r < 3; ++r)
        for (int c = 0; c < 3; ++c)
            TM[r][c] = Rwc[r][0] * M[0][c] + Rwc[r][1] * M[1][c] + Rwc[r][2] * M[2][c];
    float CC[3][3];
    for (int r = 0; r < 3; ++r)
        for (int c = 0; c < 3; ++c)
            CC[r][c] = TM[r][0] * Rwc[c][0] + TM[r][1] * Rwc[c][1] + TM[r][2] * Rwc[c][2];

    float J0[3] = {fx * izc, 0.0f, -fx * px * izc * izc};
    float J1[3] = {0.0f, fy * izc, -fy * py * izc * izc};
    float t0[3], t1[3];
    for (int c = 0; c < 3; ++c) {
        t0[c] = J0[0] * CC[0][c] + J0[1] * CC[1][c] + J0[2] * CC[2][c];
        t1[c] = J1[0] * CC[0][c] + J1[1] * CC[1][c] + J1[2] * CC[2][c];
    }
    float a  = t0[0] * J0[0] + t0[1] * J0[1] + t0[2] * J0[2] + 0.3f;
    float bq = t0[0] * J1[0] + t0[1] * J1[1] + t0[2] * J1[2];
    float cq = t1[0] * J1[0] + t1[1] * J1[1] + t1[2] * J1[2] + 0.3f;
    float det = fmaxf(a * cq - bq * bq, 1e-12f);
    float idet = 1.0f / det;
    float cA = cq * idet, cB = -bq * idet, cCc = a * idet;

    float o  = ldin(opac, i, is32);
    float op = valid ? (1.0f / (1.0f + __expf(-o))) : 0.0f;
    rec[0] = u;  rec[1] = v;
    rec[2] = -0.5f * cA;
    rec[3] = -cB;
    rec[4] = -0.5f * cCc;
    rec[5] = op;
    rec[6] = fminf(fmaxf(ldin(colors, 3 * i, is32), 0.f), 1.f);
    rec[7] = fminf(fmaxf(ldin(colors, 3 * i + 1, is32), 0.f), 1.f);
    rec[8] = fminf(fmaxf(ldin(colors, 3 * i + 2, is32), 0.f), 1.f);
    rec[9] = 0.f; rec[10] = 0.f; rec[11] = 0.f;
}

// ------------------- K1: keys + preprocess + rank + scatter (fused, 64 blocks)
// Every block recomputes all 2048 depth keys (cheap: 3 fma each; identical
// instructions in every block => all blocks agree on the ordering), does full
// preprocess for its own 32 gaussians on one wave, ranks them against all keys
// (unique key = depth_bits<<32 | idx reproduces stable argsort), and scatters
// 48-B records to params_sorted[rank].
__global__ __launch_bounds__(256) void gs_prep_rank(
    const void* __restrict__ means,
    const void* __restrict__ log_scales,
    const void* __restrict__ rots,
    const void* __restrict__ colors,
    const void* __restrict__ opac,
    const void* __restrict__ intr,
    const void* __restrict__ c2w,
    int n,
    float* __restrict__ params_sorted)
{
    __shared__ unsigned long long sk[NMAX];   // 16 KB
    __shared__ float sp32[32][12];            // 1.5 KB
    __shared__ int pr[32][9];                 // +1 pad
    __shared__ int rk[32];
    int t = threadIdx.x;
    bool is32 = detect32(intr);

    // phase A: all 2048 depth keys (z row of camera only)
    {
        float r20 = ldin(c2w, 2, is32);
        float r21 = ldin(c2w, 6, is32);
        float r22 = ldin(c2w, 10, is32);
        float tc0 = ldin(c2w, 3, is32), tc1 = ldin(c2w, 7, is32), tc2 = ldin(c2w, 11, is32);
        float tw2 = -(r20 * tc0 + r21 * tc1 + r22 * tc2);
        #pragma unroll
        for (int e = 0; e < 8; ++e) {
            int i = t + e * 256;
            unsigned long long key;
            if (i < n) {
                float mx = ldin(means, 3 * i, is32);
                float my = ldin(means, 3 * i + 1, is32);
                float mz = ldin(means, 3 * i + 2, is32);
                float pz = r20 * mx + r21 * my + r22 * mz + tw2;
                float zc = fmaxf(pz, NEARP);
                float zkey = (pz > NEARP) ? zc : __builtin_inff();
                key = (((unsigned long long)__float_as_uint(zkey)) << 32) | (unsigned int)i;
            } else {
                key = (((unsigned long long)0x7f800000u) << 32) | (unsigned int)i;
            }
            sk[i] = key;
        }
    }
    __syncthreads();

    int g0 = blockIdx.x * 32;

    // phase B: full preprocess of this block's 32 gaussians (lanes 0..31 of wave 0)
    if (t < 32) {
        int i = g0 + t;
        float rec[12];
        if (i < n) {
            preprocess_one(means, log_scales, rots, colors, opac, intr, c2w, i, is32, rec);
        } else {
            #pragma unroll
            for (int k = 0; k < 12; ++k) rec[k] = 0.f;
        }
        #pragma unroll
        for (int k = 0; k < 12; ++k) sp32[t][k] = rec[k];
    }

    // phase C: rank counts (8 interleaved chunks per gaussian; 8-lane broadcast
    // groups over consecutive u64 -> conflict-free)
    {
        int gi = t >> 3;
        int c  = t & 7;
        unsigned long long mykey = sk[g0 + gi];
        int cnt = 0;
        #pragma unroll 8
        for (int j = c; j < NMAX; j += 8)
            cnt += (sk[j] < mykey) ? 1 : 0;
        pr[gi][c] = cnt;
    }
    __syncthreads();

    if (t < 32) {
        int r = 0;
        #pragma unroll
        for (int k = 0; k < 8; ++k) r += pr[t][k];
        rk[t] = r;
    }
    __syncthreads();

    // scatter 32 records (3 float4 each) cooperatively
    if (t < 96) {
        int g = t / 3, q = t % 3;
        ((float4*)params_sorted)[rk[g] * 3 + q] = ((const float4*)sp32[g])[q];
    }
}

// --------------- K2: render + combine (fused; 256 blocks x 64 px x 4 quarters)
// Wave q composites depth-quarter q (512 sorted gaussians) for 64 pixels —
// all lanes read the same LDS record (broadcast, conflict-free). Gaussians
// staged in 4 rounds of 512 records (24 KB) to stay under the 64 KB static
// LDS limit. Quarter partials (r,g,b,T) combined in-block via LDS epilogue.
__global__ __launch_bounds__(256) void gs_render_fused(
    const float* __restrict__ params_sorted,
    void* __restrict__ out,
    const void* __restrict__ intr)
{
    __shared__ float sp[512 * 12];     // 24 KB
    __shared__ float4 res[4][64];      // 4 KB
    int t = threadIdx.x;
    int q = t >> 6;        // depth quarter == wave id
    int p = t & 63;        // pixel lane
    int pid = blockIdx.x * 64 + p;     // 64 consecutive px (within one row)
    float pxf = (float)(pid & (WW - 1));
    float pyf = (float)(pid >> 7);

    float T = 1.f, r = 0.f, g = 0.f, b = 0.f;
    for (int k = 0; k < 4; ++k) {
        __syncthreads();   // previous round's LDS reads complete
        // stage round k: quarter qq's ranks [qq*512 + k*128, +128) -> sp[qq*128*12 ...]
        #pragma unroll
        for (int j = t; j < 1536; j += 256) {
            int qq = j / 384;
            int w  = j - qq * 384;
            ((float4*)sp)[qq * 384 + w] =
                ((const float4*)params_sorted)[(qq * 512 + k * 128) * 3 + w];
        }
        __syncthreads();

        const float* base = sp + q * 128 * 12;
        #pragma unroll 4
        for (int i = 0; i < 128; ++i) {
            const float* gp = base + i * 12;
            float4 A = *(const float4*)(gp);       // u v na nb
            float4 B = *(const float4*)(gp + 4);   // nc op cr cg
            float4 C = *(const float4*)(gp + 8);   // cb - - -
            float dy    = pyf - A.y;
            float nbdy  = A.w * dy;
            float ncdy2 = (B.x * dy) * dy;
            float dx = pxf - A.x;
            float pw = fmaf(fmaf(A.z, dx, nbdy), dx, ncdy2);
            pw = fminf(pw, 0.0f);
            float al = fminf(B.y * __expf(pw), 0.99f);
            float w0 = al * T;
            r = fmaf(w0, B.z, r);
            g = fmaf(w0, B.w, g);
            b = fmaf(w0, C.x, b);
            T *= (1.0f - al);
        }
    }
    res[q][p] = make_float4(r, g, b, T);
    __syncthreads();

    if (t < 64) {
        bool is32 = detect32(intr);
        float4 a0 = res[0][t];
        float rr = a0.x, gg = a0.y, bb = a0.z, Tt = a0.w;
        #pragma unroll
        for (int s = 1; s < 4; ++s) {
            float4 as = res[s][t];
            rr = fmaf(Tt, as.x, rr);
            gg = fmaf(Tt, as.y, gg);
            bb = fmaf(Tt, as.z, bb);
            Tt *= as.w;
        }
        int opid = blockIdx.x * 64 + t;
        stout(out, opid * 3 + 0, rr, is32);
        stout(out, opid * 3 + 1, gg, is32);
        stout(out, opid * 3 + 2, bb, is32);
    }
}

extern "C" void kernel_launch(void* const* d_in, const int* in_sizes, int n_in,
                              void* d_out, int out_size, void* d_ws, size_t ws_size,
                              hipStream_t stream)
{
    const void* means      = d_in[0];
    const void* log_scales = d_in[1];
    const void* rotations  = d_in[2];
    const void* colors     = d_in[3];
    const void* opacities  = d_in[4];
    const void* intrinsics = d_in[5];
    const void* cam2world  = d_in[6];

    int n = in_sizes[4];
    if (n > NMAX) n = NMAX;
    if (ws_size < (size_t)NMAX * 48) return;   // never triggers (ws is 268 MB)

    float* sortedp = (float*)d_ws;   // 96 KB sorted records

    gs_prep_rank<<<NMAX / 32, 256, 0, stream>>>(
        means, log_scales, rotations, colors, opacities, intrinsics, cam2world,
        n, sortedp);
    gs_render_fused<<<HH * WW / 64, 256, 0, stream>>>(sortedp, d_out, intrinsics);
}